// Round 5
// baseline (487.131 us; speedup 1.0000x reference)
//
#include <hip/hip_runtime.h>
#include <math.h>

#define B_ 2
#define C_ 32
#define D_ 64
#define H_ 128
#define W_ 128
#define N_ (D_*H_*W_)          // 1048576 = 2^20
#define NW_ (N_/64)            // 16384 words per image
#define P_CAP 2048
#define NEG_CAP 12288
#define PAD 5
#define EPS_ 1e-8f
#define SLICES 64
#define TA 4                   // anchors per thread

// ---------------- pack fg bits + W-axis dilation (bitwise) + init ----------------
__global__ __launch_bounds__(256) void k_packW(const int* __restrict__ labels,
                                               unsigned long long* __restrict__ fgbits,
                                               unsigned long long* __restrict__ dilw,
                                               int* cnt_pos, int* cnt_neg,
                                               float* loss_sum, float* acnt) {
    if (blockIdx.x == 0 && threadIdx.x < B_) {
        int t = threadIdx.x;
        cnt_pos[t] = 0; cnt_neg[t] = 0; loss_sum[t] = 0.f; acnt[t] = 0.f;
    }
    const int g = blockIdx.x * 256 + threadIdx.x;
    const int lane = threadIdx.x & 63;
    const int w = threadIdx.x >> 6;            // wave id 0..3
    const int word = (blockIdx.x << 2) + w;    // global word index = g>>6

    unsigned long long fgw = __ballot(labels[g] > 0);
    __shared__ unsigned long long smem[4];
    if (lane == 0) { fgbits[word] = fgw; smem[w] = fgw; }
    __syncthreads();
    unsigned long long self = smem[w];
    unsigned long long other = smem[w ^ 1];
    unsigned long long out = self;
    if ((word & 1) == 0) {       // low word of the 128-bit row
#pragma unroll
        for (int k = 1; k <= PAD; ++k)
            out |= (self >> k) | (self << k) | (other << (64 - k));
    } else {                     // high word
#pragma unroll
        for (int k = 1; k <= PAD; ++k)
            out |= (self << k) | (self >> k) | (other >> (64 - k));
    }
    if (lane == 0) dilw[word] = out;
}

// ---------------- H-axis dilation on words ----------------
__global__ __launch_bounds__(256) void k_dilH(const unsigned long long* __restrict__ in,
                                              unsigned long long* __restrict__ out) {
    const int q = blockIdx.x * 256 + threadIdx.x;       // 0..B_*NW_-1
    const int qq = q & (NW_ - 1);
    const int h = (qq >> 1) & (H_ - 1);
    const int lo = (h >= PAD) ? -PAD : -h;
    const int hi = (h + PAD <= H_ - 1) ? PAD : (H_ - 1 - h);
    unsigned long long v = 0;
    for (int o = lo; o <= hi; ++o) v |= in[q + o * 2];
    out[q] = v;
}

// ---------------- D-axis dilation on words ----------------
__global__ __launch_bounds__(256) void k_dilD(const unsigned long long* __restrict__ in,
                                              unsigned long long* __restrict__ out) {
    const int q = blockIdx.x * 256 + threadIdx.x;
    const int qq = q & (NW_ - 1);
    const int d = qq >> 8;                               // d = qq / (H_*2)
    const int lo = (d >= PAD) ? -PAD : -d;
    const int hi = (d + PAD <= D_ - 1) ? PAD : (D_ - 1 - d);
    unsigned long long v = 0;
    for (int o = lo; o <= hi; ++o) v |= in[q + o * (H_ * 2)];
    out[q] = v;
}

// ---------------- fused compact + gather + normalize ----------------
__global__ __launch_bounds__(256) void k_cg(const float* __restrict__ features,
                                            const unsigned long long* __restrict__ fgbits,
                                            const unsigned long long* __restrict__ dild,
                                            int* cnt_pos, int* cnt_neg,
                                            float* __restrict__ pos_feat,
                                            float* __restrict__ neg_feat) {
    const int g = blockIdx.x * 256 + threadIdx.x;
    const int lane = threadIdx.x & 63;
    const int word = g >> 6;
    const int b = g >> 20;
    const int n = g & (N_ - 1);

    unsigned long long fgw = fgbits[word];               // wave-uniform load
    unsigned long long rimw = dild[word] & ~fgw;
    if ((fgw | rimw) == 0) return;

    int basep = 0, basen = 0;
    if (lane == 0) {
        if (fgw)  basep = atomicAdd(&cnt_pos[b], __popcll(fgw));
        if (rimw) basen = atomicAdd(&cnt_neg[b], __popcll(rimw));
    }
    basep = __shfl(basep, 0);
    basen = __shfl(basen, 0);

    const unsigned long long ltmask = (lane == 0) ? 0ull : (~0ull >> (64 - lane));
    const bool is_fg = (fgw >> lane) & 1;
    const bool is_rim = (rimw >> lane) & 1;
    if (!is_fg && !is_rim) return;

    int slot; float* dst;
    if (is_fg) {
        slot = basep + __popcll(fgw & ltmask);
        if (slot >= P_CAP) return;
        dst = pos_feat + ((size_t)b * P_CAP + slot) * C_;
    } else {
        slot = basen + __popcll(rimw & ltmask);
        if (slot >= NEG_CAP) return;
        dst = neg_feat + ((size_t)b * NEG_CAP + slot) * C_;
    }

    const float* fbase = features + (size_t)b * C_ * N_ + n;
    float v[C_];
    float ss = 0.f;
#pragma unroll
    for (int c = 0; c < C_; ++c) {
        float x = fbase[(size_t)c * N_];
        v[c] = x;
        ss += x * x;
    }
    float inv = 1.0f / fmaxf(sqrtf(ss), 1e-12f);
#pragma unroll
    for (int c = 0; c < C_; ++c) dst[c] = v[c] * inv;
}

// ---------------- partner-sliced loss, fixed softmax shift m=10 ----------------
// partial layout: [B][SLICES][2][P_CAP]
__device__ __forceinline__ void dot4x(const float4* __restrict__ row4,
                                      const float A[TA][C_], float d[TA]) {
    d[0] = d[1] = d[2] = d[3] = 0.f;
#pragma unroll
    for (int q = 0; q < 8; ++q) {
        float4 v = row4[q];
#pragma unroll
        for (int i = 0; i < TA; ++i) {
            d[i] = fmaf(v.x, A[i][4*q+0], d[i]);
            d[i] = fmaf(v.y, A[i][4*q+1], d[i]);
            d[i] = fmaf(v.z, A[i][4*q+2], d[i]);
            d[i] = fmaf(v.w, A[i][4*q+3], d[i]);
        }
    }
}

__global__ __launch_bounds__(256, 3) void k_loss2(const float* __restrict__ pos_feat,
                                                  const float* __restrict__ neg_feat,
                                                  const int* __restrict__ cnt_pos,
                                                  const int* __restrict__ cnt_neg,
                                                  float* __restrict__ partial) {
    const int slice = blockIdx.x;
    const int tile  = blockIdx.y;
    const int b     = blockIdx.z;
    const int np = min(cnt_pos[b], P_CAP);
    const int nn = min(cnt_neg[b], NEG_CAP);
    const int abase = tile * 256;
    if (abase >= np) return;
    const int total = np + nn;
    const int tid = threadIdx.x;
    const int lane = tid & 63;
    const int w = __builtin_amdgcn_readfirstlane(tid >> 6);

    // ---- stage the 256-anchor tile through LDS (coalesced global load) ----
    __shared__ float sA[256 * C_];               // 32 KB, row stride 32 floats
    {
        const float4* src = (const float4*)(pos_feat + ((size_t)b * P_CAP + abase) * C_);
        float4* dstl = (float4*)sA;
#pragma unroll
        for (int idx = tid, k = 0; k < 8; ++k, idx += 256)
            dstl[idx] = src[idx];
    }
    __syncthreads();

    // ---- register fill from LDS, lane-rotated chunk order (conflict-free) ----
    const int a0 = abase + lane * TA;
    float A[TA][C_];
#pragma unroll
    for (int i = 0; i < TA; ++i) {
        const int r = lane * TA + i;
#pragma unroll
        for (int qq = 0; qq < 8; ++qq) {
            const int q = (qq + lane) & 7;
            float4 v = *(const float4*)&sA[r * C_ + q * 4];
            A[i][4*q+0] = v.x; A[i][4*q+1] = v.y; A[i][4*q+2] = v.z; A[i][4*q+3] = v.w;
        }
    }
    __syncthreads();   // sA reused below as reduction scratch

    float ps[TA] = {0.f, 0.f, 0.f, 0.f};
    float ns[TA] = {0.f, 0.f, 0.f, 0.f};

    const int per = (total + SLICES - 1) / SLICES;
    const int r0 = slice * per;
    const int r1 = min(r0 + per, total);

    // ---- positive partners in [r0, min(r1,np)) ----
    const int pEnd = min(r1, np);
    const float4* pbase4 = (const float4*)(pos_feat + (size_t)b * P_CAP * C_);
    for (int gr = r0 + w; gr < pEnd; gr += 4) {
        float d[TA];
        dot4x(pbase4 + gr * 8, A, d);
#pragma unroll
        for (int i = 0; i < TA; ++i) {
            float e = __expf(fmaf(d[i], 10.f, -10.f));
            ps[i] += (gr == a0 + i) ? 0.f : e;
        }
    }
    // ---- negative partners in [max(r0,np), r1) ----
    const int s0 = max(r0, np);
    const float4* nbase4 = (const float4*)(neg_feat + (size_t)b * NEG_CAP * C_);
    for (int gr = s0 + w; gr < r1; gr += 4) {
        float d[TA];
        dot4x(nbase4 + (gr - np) * 8, A, d);
#pragma unroll
        for (int i = 0; i < TA; ++i)
            ns[i] += __expf(fmaf(d[i], 10.f, -10.f));
    }

    // ---- cross-wave reduction (reuse sA as scratch: 4 waves x 256 x 2) ----
    float* redP = sA;                 // [4][256]
    float* redN = sA + 4 * 256;       // [4][256]
    const int slot = lane * TA;
#pragma unroll
    for (int i = 0; i < TA; ++i) { redP[w * 256 + slot + i] = ps[i]; redN[w * 256 + slot + i] = ns[i]; }
    __syncthreads();
    {
        float p = redP[0*256 + tid] + redP[1*256 + tid] + redP[2*256 + tid] + redP[3*256 + tid];
        float n = redN[0*256 + tid] + redN[1*256 + tid] + redN[2*256 + tid] + redN[3*256 + tid];
        float* dst = partial + ((size_t)(b * SLICES + slice) * 2) * P_CAP;
        dst[abase + tid] = p;
        dst[P_CAP + abase + tid] = n;
    }
}

// ---------------- per-anchor finalize ----------------
__global__ __launch_bounds__(256) void k_loss_fin(const float* __restrict__ partial,
                                                  const int* __restrict__ cnt_pos,
                                                  float* __restrict__ loss_sum,
                                                  float* __restrict__ acnt) {
    const int blocks_per_b = P_CAP / 256;
    const int b = blockIdx.x / blocks_per_b;
    const int a = (blockIdx.x % blocks_per_b) * 256 + threadIdx.x;
    const int np = min(cnt_pos[b], P_CAP);
    const int tid = threadIdx.x;
    float loss = 0.f, cnt = 0.f;
    if (a < np) {
        float num = 0.f, den = 0.f;
        for (int s = 0; s < SLICES; ++s) {
            const float* base = partial + ((size_t)(b * SLICES + s) * 2) * P_CAP;
            num += base[a];
            den += base[P_CAP + a];
        }
        if (num > 0.f) {
            den += num;
            num += EPS_; den += EPS_;
            loss = __logf(den) - __logf(num);
            cnt = 1.f;
        }
    }
    __shared__ float sl[256], sc[256];
    sl[tid] = loss; sc[tid] = cnt;
    __syncthreads();
    for (int off = 128; off > 0; off >>= 1) {
        if (tid < off) { sl[tid] += sl[tid + off]; sc[tid] += sc[tid + off]; }
        __syncthreads();
    }
    if (tid == 0 && sc[0] > 0.f) {
        atomicAdd(&loss_sum[b], sl[0]);
        atomicAdd(&acnt[b], sc[0]);
    }
}

// ---------------- finalize ----------------
__global__ void k_final(const int* cnt_pos, const int* cnt_neg,
                        const float* loss_sum, const float* acnt, float* out) {
    float tot = 0.f, nv = 0.f;
    bool any = false;
    for (int b = 0; b < B_; ++b) {
        bool valid = (cnt_pos[b] >= 2) && (cnt_neg[b] > 0) && (acnt[b] > 0.f);
        float il = loss_sum[b] / fmaxf(acnt[b], 1.f);
        if (valid) { tot += il; nv += 1.f; any = true; }
    }
    out[0] = any ? tot / fmaxf(nv, 1.f) : 0.f;
}

extern "C" void kernel_launch(void* const* d_in, const int* in_sizes, int n_in,
                              void* d_out, int out_size, void* d_ws, size_t ws_size,
                              hipStream_t stream) {
    const float* features = (const float*)d_in[0];
    const int* labels = (const int*)d_in[1];
    float* out = (float*)d_out;

    // ---- workspace carve ----
    char* p = (char*)d_ws;
    float* pos_feat = (float*)p;                 p += (size_t)B_ * P_CAP * C_ * 4;
    float* neg_feat = (float*)p;                 p += (size_t)B_ * NEG_CAP * C_ * 4;
    float* partial = (float*)p;                  p += (size_t)B_ * SLICES * 2 * P_CAP * 4;
    unsigned long long* fgbits = (unsigned long long*)p;  p += (size_t)B_ * NW_ * 8;
    unsigned long long* dilw = (unsigned long long*)p;    p += (size_t)B_ * NW_ * 8;
    unsigned long long* dilh = (unsigned long long*)p;    p += (size_t)B_ * NW_ * 8;
    unsigned long long* dild = (unsigned long long*)p;    p += (size_t)B_ * NW_ * 8;
    int* cnt_pos = (int*)p;                      p += B_ * 4;
    int* cnt_neg = (int*)p;                      p += B_ * 4;
    float* loss_sum = (float*)p;                 p += B_ * 4;
    float* acnt = (float*)p;                     p += B_ * 4;

    const int threads = 256;
    const int vox_blocks = B_ * N_ / threads;          // 8192
    const int word_blocks = B_ * NW_ / threads;        // 128

    k_packW<<<vox_blocks, threads, 0, stream>>>(labels, fgbits, dilw,
                                                cnt_pos, cnt_neg, loss_sum, acnt);
    k_dilH<<<word_blocks, threads, 0, stream>>>(dilw, dilh);
    k_dilD<<<word_blocks, threads, 0, stream>>>(dilh, dild);
    k_cg<<<vox_blocks, threads, 0, stream>>>(features, fgbits, dild,
                                             cnt_pos, cnt_neg, pos_feat, neg_feat);
    dim3 lgrid(SLICES, P_CAP / 256, B_);
    k_loss2<<<lgrid, 256, 0, stream>>>(pos_feat, neg_feat, cnt_pos, cnt_neg, partial);
    k_loss_fin<<<B_ * (P_CAP / 256), 256, 0, stream>>>(partial, cnt_pos, loss_sum, acnt);
    k_final<<<1, 1, 0, stream>>>(cnt_pos, cnt_neg, loss_sum, acnt, out);
}

// Round 6
// 371.083 us; speedup vs baseline: 1.3127x; 1.3127x over previous
//
#include <hip/hip_runtime.h>
#include <math.h>

#define B_ 2
#define C_ 32
#define D_ 64
#define H_ 128
#define W_ 128
#define N_ (D_*H_*W_)          // 1048576 = 2^20
#define NW_ (N_/64)            // 16384 words per image
#define P_CAP 2048
#define NEG_CAP 12288
#define PAD 5
#define EPS_ 1e-8f
#define SLICES 64
#define TA 4                   // anchors per thread

// ---------------- pack fg bits + W-axis dilation (bitwise) + init ----------------
__global__ __launch_bounds__(256) void k_packW(const int* __restrict__ labels,
                                               unsigned long long* __restrict__ fgbits,
                                               unsigned long long* __restrict__ dilw,
                                               int* cnt_pos, int* cnt_neg,
                                               float* loss_sum, float* acnt) {
    if (blockIdx.x == 0 && threadIdx.x < B_) {
        int t = threadIdx.x;
        cnt_pos[t] = 0; cnt_neg[t] = 0; loss_sum[t] = 0.f; acnt[t] = 0.f;
    }
    const int g = blockIdx.x * 256 + threadIdx.x;
    const int lane = threadIdx.x & 63;
    const int w = threadIdx.x >> 6;            // wave id 0..3
    const int word = (blockIdx.x << 2) + w;    // global word index = g>>6

    unsigned long long fgw = __ballot(labels[g] > 0);
    __shared__ unsigned long long smem[4];
    if (lane == 0) { fgbits[word] = fgw; smem[w] = fgw; }
    __syncthreads();
    unsigned long long self = smem[w];
    unsigned long long other = smem[w ^ 1];
    unsigned long long out = self;
    if ((word & 1) == 0) {       // low word of the 128-bit row
#pragma unroll
        for (int k = 1; k <= PAD; ++k)
            out |= (self >> k) | (self << k) | (other << (64 - k));
    } else {                     // high word
#pragma unroll
        for (int k = 1; k <= PAD; ++k)
            out |= (self << k) | (self >> k) | (other >> (64 - k));
    }
    if (lane == 0) dilw[word] = out;
}

// ---------------- H-axis dilation on words ----------------
__global__ __launch_bounds__(256) void k_dilH(const unsigned long long* __restrict__ in,
                                              unsigned long long* __restrict__ out) {
    const int q = blockIdx.x * 256 + threadIdx.x;       // 0..B_*NW_-1
    const int qq = q & (NW_ - 1);
    const int h = (qq >> 1) & (H_ - 1);
    const int lo = (h >= PAD) ? -PAD : -h;
    const int hi = (h + PAD <= H_ - 1) ? PAD : (H_ - 1 - h);
    unsigned long long v = 0;
    for (int o = lo; o <= hi; ++o) v |= in[q + o * 2];
    out[q] = v;
}

// ---------------- D-axis dilation on words ----------------
__global__ __launch_bounds__(256) void k_dilD(const unsigned long long* __restrict__ in,
                                              unsigned long long* __restrict__ out) {
    const int q = blockIdx.x * 256 + threadIdx.x;
    const int qq = q & (NW_ - 1);
    const int d = qq >> 8;                               // d = qq / (H_*2)
    const int lo = (d >= PAD) ? -PAD : -d;
    const int hi = (d + PAD <= D_ - 1) ? PAD : (D_ - 1 - d);
    unsigned long long v = 0;
    for (int o = lo; o <= hi; ++o) v |= in[q + o * (H_ * 2)];
    out[q] = v;
}

// ---------------- fused compact + gather + normalize ----------------
__global__ __launch_bounds__(256) void k_cg(const float* __restrict__ features,
                                            const unsigned long long* __restrict__ fgbits,
                                            const unsigned long long* __restrict__ dild,
                                            int* cnt_pos, int* cnt_neg,
                                            float* __restrict__ pos_feat,
                                            float* __restrict__ neg_feat) {
    const int g = blockIdx.x * 256 + threadIdx.x;
    const int lane = threadIdx.x & 63;
    const int word = g >> 6;
    const int b = g >> 20;
    const int n = g & (N_ - 1);

    unsigned long long fgw = fgbits[word];               // wave-uniform load
    unsigned long long rimw = dild[word] & ~fgw;
    if ((fgw | rimw) == 0) return;

    int basep = 0, basen = 0;
    if (lane == 0) {
        if (fgw)  basep = atomicAdd(&cnt_pos[b], __popcll(fgw));
        if (rimw) basen = atomicAdd(&cnt_neg[b], __popcll(rimw));
    }
    basep = __shfl(basep, 0);
    basen = __shfl(basen, 0);

    const unsigned long long ltmask = (lane == 0) ? 0ull : (~0ull >> (64 - lane));
    const bool is_fg = (fgw >> lane) & 1;
    const bool is_rim = (rimw >> lane) & 1;
    if (!is_fg && !is_rim) return;

    int slot; float* dst;
    if (is_fg) {
        slot = basep + __popcll(fgw & ltmask);
        if (slot >= P_CAP) return;
        dst = pos_feat + ((size_t)b * P_CAP + slot) * C_;
    } else {
        slot = basen + __popcll(rimw & ltmask);
        if (slot >= NEG_CAP) return;
        dst = neg_feat + ((size_t)b * NEG_CAP + slot) * C_;
    }

    const float* fbase = features + (size_t)b * C_ * N_ + n;
    float v[C_];
    float ss = 0.f;
#pragma unroll
    for (int c = 0; c < C_; ++c) {
        float x = fbase[(size_t)c * N_];
        v[c] = x;
        ss += x * x;
    }
    float inv = 1.0f / fmaxf(sqrtf(ss), 1e-12f);
#pragma unroll
    for (int c = 0; c < C_; ++c) dst[c] = v[c] * inv;
}

// ---------------- partner-sliced loss, fixed softmax shift m=10 ----------------
// partial layout: [B][SLICES][2][P_CAP]
__device__ __forceinline__ void dot4x(const float4* __restrict__ row4,
                                      const float A[TA][C_], float d[TA]) {
    d[0] = d[1] = d[2] = d[3] = 0.f;
#pragma unroll
    for (int q = 0; q < 8; ++q) {
        float4 v = row4[q];
#pragma unroll
        for (int i = 0; i < TA; ++i) {
            d[i] = fmaf(v.x, A[i][4*q+0], d[i]);
            d[i] = fmaf(v.y, A[i][4*q+1], d[i]);
            d[i] = fmaf(v.z, A[i][4*q+2], d[i]);
            d[i] = fmaf(v.w, A[i][4*q+3], d[i]);
        }
    }
}

__global__ __launch_bounds__(256, 3) void k_loss2(const float* __restrict__ pos_feat,
                                                  const float* __restrict__ neg_feat,
                                                  const int* __restrict__ cnt_pos,
                                                  const int* __restrict__ cnt_neg,
                                                  float* __restrict__ partial) {
    const int slice = blockIdx.x;
    const int tile  = blockIdx.y;
    const int b     = blockIdx.z;
    const int np = min(cnt_pos[b], P_CAP);
    const int nn = min(cnt_neg[b], NEG_CAP);
    const int abase = tile * 256;
    if (abase >= np) return;
    const int total = np + nn;
    const int tid = threadIdx.x;
    const int lane = tid & 63;
    const int w = __builtin_amdgcn_readfirstlane(tid >> 6);

    // ---- stage the 256-anchor tile through LDS, XOR-swizzled chunks ----
    // chunk q (float4) of row r lives at sA4[r*8 + ((q + r) & 7)]
    __shared__ float4 sA4[256 * 8];               // 32 KB
    {
        const float4* src = (const float4*)(pos_feat + ((size_t)b * P_CAP + abase) * C_);
#pragma unroll
        for (int k = 0; k < 8; ++k) {
            const int idx = tid + k * 256;        // linear float4 index (coalesced read)
            const int r = idx >> 3, q = idx & 7;
            sA4[(r << 3) | ((q + r) & 7)] = src[idx];
        }
    }
    __syncthreads();

    // ---- register fill from LDS: thread owns rows r_i = i*64 + lane ----
    // static q indices -> A stays in VGPRs; swizzle spreads banks (2 lanes/bank = free)
    float A[TA][C_];
#pragma unroll
    for (int i = 0; i < TA; ++i) {
        const int r = i * 64 + lane;
        const int rbase = r << 3;
        const int rot = r & 7;
#pragma unroll
        for (int q = 0; q < 8; ++q) {
            float4 v = sA4[rbase | ((q + rot) & 7)];
            A[i][4*q+0] = v.x; A[i][4*q+1] = v.y; A[i][4*q+2] = v.z; A[i][4*q+3] = v.w;
        }
    }
    __syncthreads();   // sA4 reused below as reduction scratch

    float ps[TA] = {0.f, 0.f, 0.f, 0.f};
    float ns[TA] = {0.f, 0.f, 0.f, 0.f};

    const int per = (total + SLICES - 1) / SLICES;
    const int r0 = slice * per;
    const int r1 = min(r0 + per, total);
    const int a1 = abase + lane;                 // anchor i is a1 + 64*i

    // ---- positive partners in [r0, min(r1,np)) ----
    const int pEnd = min(r1, np);
    const float4* pbase4 = (const float4*)(pos_feat + (size_t)b * P_CAP * C_);
    for (int gr = r0 + w; gr < pEnd; gr += 4) {
        float d[TA];
        dot4x(pbase4 + gr * 8, A, d);
#pragma unroll
        for (int i = 0; i < TA; ++i) {
            float e = __expf(fmaf(d[i], 10.f, -10.f));
            ps[i] += (gr == a1 + 64 * i) ? 0.f : e;
        }
    }
    // ---- negative partners in [max(r0,np), r1) ----
    const int s0 = max(r0, np);
    const float4* nbase4 = (const float4*)(neg_feat + (size_t)b * NEG_CAP * C_);
    for (int gr = s0 + w; gr < r1; gr += 4) {
        float d[TA];
        dot4x(nbase4 + (gr - np) * 8, A, d);
#pragma unroll
        for (int i = 0; i < TA; ++i)
            ns[i] += __expf(fmaf(d[i], 10.f, -10.f));
    }

    // ---- cross-wave reduction (reuse sA4 as scratch: [4][256] x 2) ----
    float* redP = (float*)sA4;           // [4][256]
    float* redN = (float*)sA4 + 4 * 256; // [4][256]
#pragma unroll
    for (int i = 0; i < TA; ++i) {
        redP[w * 256 + i * 64 + lane] = ps[i];
        redN[w * 256 + i * 64 + lane] = ns[i];
    }
    __syncthreads();
    {
        float p = redP[0*256 + tid] + redP[1*256 + tid] + redP[2*256 + tid] + redP[3*256 + tid];
        float n = redN[0*256 + tid] + redN[1*256 + tid] + redN[2*256 + tid] + redN[3*256 + tid];
        float* dst = partial + ((size_t)(b * SLICES + slice) * 2) * P_CAP;
        dst[abase + tid] = p;
        dst[P_CAP + abase + tid] = n;
    }
}

// ---------------- per-anchor finalize ----------------
__global__ __launch_bounds__(256) void k_loss_fin(const float* __restrict__ partial,
                                                  const int* __restrict__ cnt_pos,
                                                  float* __restrict__ loss_sum,
                                                  float* __restrict__ acnt) {
    const int blocks_per_b = P_CAP / 256;
    const int b = blockIdx.x / blocks_per_b;
    const int a = (blockIdx.x % blocks_per_b) * 256 + threadIdx.x;
    const int np = min(cnt_pos[b], P_CAP);
    const int tid = threadIdx.x;
    float loss = 0.f, cnt = 0.f;
    if (a < np) {
        float num = 0.f, den = 0.f;
        for (int s = 0; s < SLICES; ++s) {
            const float* base = partial + ((size_t)(b * SLICES + s) * 2) * P_CAP;
            num += base[a];
            den += base[P_CAP + a];
        }
        if (num > 0.f) {
            den += num;
            num += EPS_; den += EPS_;
            loss = __logf(den) - __logf(num);
            cnt = 1.f;
        }
    }
    __shared__ float sl[256], sc[256];
    sl[tid] = loss; sc[tid] = cnt;
    __syncthreads();
    for (int off = 128; off > 0; off >>= 1) {
        if (tid < off) { sl[tid] += sl[tid + off]; sc[tid] += sc[tid + off]; }
        __syncthreads();
    }
    if (tid == 0 && sc[0] > 0.f) {
        atomicAdd(&loss_sum[b], sl[0]);
        atomicAdd(&acnt[b], sc[0]);
    }
}

// ---------------- finalize ----------------
__global__ void k_final(const int* cnt_pos, const int* cnt_neg,
                        const float* loss_sum, const float* acnt, float* out) {
    float tot = 0.f, nv = 0.f;
    bool any = false;
    for (int b = 0; b < B_; ++b) {
        bool valid = (cnt_pos[b] >= 2) && (cnt_neg[b] > 0) && (acnt[b] > 0.f);
        float il = loss_sum[b] / fmaxf(acnt[b], 1.f);
        if (valid) { tot += il; nv += 1.f; any = true; }
    }
    out[0] = any ? tot / fmaxf(nv, 1.f) : 0.f;
}

extern "C" void kernel_launch(void* const* d_in, const int* in_sizes, int n_in,
                              void* d_out, int out_size, void* d_ws, size_t ws_size,
                              hipStream_t stream) {
    const float* features = (const float*)d_in[0];
    const int* labels = (const int*)d_in[1];
    float* out = (float*)d_out;

    // ---- workspace carve ----
    char* p = (char*)d_ws;
    float* pos_feat = (float*)p;                 p += (size_t)B_ * P_CAP * C_ * 4;
    float* neg_feat = (float*)p;                 p += (size_t)B_ * NEG_CAP * C_ * 4;
    float* partial = (float*)p;                  p += (size_t)B_ * SLICES * 2 * P_CAP * 4;
    unsigned long long* fgbits = (unsigned long long*)p;  p += (size_t)B_ * NW_ * 8;
    unsigned long long* dilw = (unsigned long long*)p;    p += (size_t)B_ * NW_ * 8;
    unsigned long long* dilh = (unsigned long long*)p;    p += (size_t)B_ * NW_ * 8;
    unsigned long long* dild = (unsigned long long*)p;    p += (size_t)B_ * NW_ * 8;
    int* cnt_pos = (int*)p;                      p += B_ * 4;
    int* cnt_neg = (int*)p;                      p += B_ * 4;
    float* loss_sum = (float*)p;                 p += B_ * 4;
    float* acnt = (float*)p;                     p += B_ * 4;

    const int threads = 256;
    const int vox_blocks = B_ * N_ / threads;          // 8192
    const int word_blocks = B_ * NW_ / threads;        // 128

    k_packW<<<vox_blocks, threads, 0, stream>>>(labels, fgbits, dilw,
                                                cnt_pos, cnt_neg, loss_sum, acnt);
    k_dilH<<<word_blocks, threads, 0, stream>>>(dilw, dilh);
    k_dilD<<<word_blocks, threads, 0, stream>>>(dilh, dild);
    k_cg<<<vox_blocks, threads, 0, stream>>>(features, fgbits, dild,
                                             cnt_pos, cnt_neg, pos_feat, neg_feat);
    dim3 lgrid(SLICES, P_CAP / 256, B_);
    k_loss2<<<lgrid, 256, 0, stream>>>(pos_feat, neg_feat, cnt_pos, cnt_neg, partial);
    k_loss_fin<<<B_ * (P_CAP / 256), 256, 0, stream>>>(partial, cnt_pos, loss_sum, acnt);
    k_final<<<1, 1, 0, stream>>>(cnt_pos, cnt_neg, loss_sum, acnt, out);
}